// Round 1
// baseline (245.702 us; speedup 1.0000x reference)
//
#include <hip/hip_runtime.h>

// YOLO-v1-style loss, exact port of the JAX reference.
// S=7, B=2, C=20, channels per cell = 30:
//   ch 0..19  : class scores
//   ch 20..24 : box0 x,y,w,h,conf
//   ch 25..29 : box1 x,y,w,h,conf
// cls part of the loss uses channels [5*B:, i.e. 10..29] (reference quirk, kept).

#define CH    30
#define EPSL  1e-6f
#define TPB   128   // threads (=cells) per block; LDS = 2*128*30*4 B = 30720 B -> 5 blocks/CU

__device__ __forceinline__ float sgnf(float x) {
    return (x > 0.0f) ? 1.0f : ((x < 0.0f) ? -1.0f : 0.0f);
}

__global__ __launch_bounds__(TPB) void yolo_loss_kernel(const float* __restrict__ p,
                                                        const float* __restrict__ a,
                                                        float* __restrict__ out,
                                                        long long n_cells) {
    __shared__ float shp[TPB * CH];
    __shared__ float sha[TPB * CH];
    __shared__ float wsum[TPB / 64];

    const int tid = threadIdx.x;
    const long long block_cell0 = (long long)blockIdx.x * TPB;
    const long long block_base  = block_cell0 * CH;          // float offset, 16B-aligned (TPB*CH*4 = 15360)
    const long long total       = n_cells * CH;

    // ---- Stage both tiles into LDS with coalesced float4 loads (16 B/lane) ----
    const float4* gp4 = (const float4*)(p + block_base);
    const float4* ga4 = (const float4*)(a + block_base);
    float4* sp4 = (float4*)shp;
    float4* sa4 = (float4*)sha;
    const int nvec = TPB * CH / 4;  // 960 float4 per tensor
    for (int i = tid; i < nvec; i += TPB) {
        if (block_base + (long long)i * 4 + 3 < total) {   // always true for exact grids; defensive
            sp4[i] = gp4[i];
            sa4[i] = ga4[i];
        }
    }
    __syncthreads();

    float lsum = 0.0f;
    const long long cell = block_cell0 + tid;
    if (cell < n_cells) {
        const float* cp = &shp[tid * CH];
        const float* ca = &sha[tid * CH];

        float pxv[2], pyv[2], pwv[2], phv[2], pcv[2];
        float axv[2], ayv[2], awv[2], ahv[2];
#pragma unroll
        for (int b = 0; b < 2; ++b) {
            pxv[b] = cp[20 + 5 * b]; pyv[b] = cp[21 + 5 * b];
            pwv[b] = cp[22 + 5 * b]; phv[b] = cp[23 + 5 * b];
            pcv[b] = cp[24 + 5 * b];
            axv[b] = ca[20 + 5 * b]; ayv[b] = ca[21 + 5 * b];
            awv[b] = ca[22 + 5 * b]; ahv[b] = ca[23 + 5 * b];
        }
        const bool obj = ca[24] > 0.0f;   // a's box-0 conf

        // ---- pairwise IoU, max over target boxes ----
        float miou[2];
#pragma unroll
        for (int pb = 0; pb < 2; ++pb) {
            const float p_tlx = pxv[pb] - 0.5f * pwv[pb];
            const float p_tly = pyv[pb] - 0.5f * phv[pb];
            const float p_brx = pxv[pb] + 0.5f * pwv[pb];
            const float p_bry = pyv[pb] + 0.5f * phv[pb];
            const float p_area = pwv[pb] * phv[pb];
            float best = -3.4e38f;
#pragma unroll
            for (int ab = 0; ab < 2; ++ab) {
                const float a_tlx = axv[ab] - 0.5f * awv[ab];
                const float a_tly = ayv[ab] - 0.5f * ahv[ab];
                const float a_brx = axv[ab] + 0.5f * awv[ab];
                const float a_bry = ayv[ab] + 0.5f * ahv[ab];
                float sx = fminf(p_brx, a_brx) - fmaxf(p_tlx, a_tlx);
                float sy = fminf(p_bry, a_bry) - fmaxf(p_tly, a_tly);
                sx = fmaxf(sx, 0.0f);
                sy = fmaxf(sy, 0.0f);
                const float inter = sx * sy;
                const float uni = p_area + awv[ab] * ahv[ab] - inter;
                const float iou = (uni == 0.0f) ? 0.0f : (inter / uni);  // where(zero,0)/where(zero,eps) == 0
                best = fmaxf(best, iou);
            }
            miou[pb] = best;
        }
        // argmax over pred boxes, first-max tie-break (jnp.argmax semantics)
        const int resp = (miou[1] > miou[0]) ? 1 : 0;

        // ---- coordinate / confidence losses ----
#pragma unroll
        for (int b = 0; b < 2; ++b) {
            const bool oij = obj && (b == resp);
            if (oij) {
                const float dx = axv[b] - pxv[b];
                const float dy = ayv[b] - pyv[b];
                const float dw = sgnf(awv[b]) * sqrtf(awv[b] + EPSL) - sgnf(pwv[b]) * sqrtf(pwv[b] + EPSL);
                const float dh = sgnf(ahv[b]) * sqrtf(ahv[b] + EPSL) - sgnf(phv[b]) * sqrtf(phv[b] + EPSL);
                const float dc = 1.0f - pcv[b];  // (obj_ij^2 - obj_ij*pc)^2 with obj_ij==1
                lsum += 5.0f * (dx * dx + dy * dy + dw * dw + dh * dh) + dc * dc;
            } else {
                // noobj term: (noobj_ij*obj_ij - noobj_ij*pc)^2 = pc^2 when obj_ij==0
                lsum += 0.5f * pcv[b] * pcv[b];
            }
        }

        // ---- "class" loss over channels 10..29, gated by obj_i ----
        if (obj) {
#pragma unroll
            for (int k = 10; k < 30; ++k) {
                const float d = cp[k] - ca[k];
                lsum += d * d;
            }
        }
    }

    // ---- reduction: wave shfl -> LDS -> one atomic per block ----
    float v = lsum;
#pragma unroll
    for (int off = 32; off > 0; off >>= 1)
        v += __shfl_down(v, off, 64);
    if ((tid & 63) == 0) wsum[tid >> 6] = v;
    __syncthreads();
    if (tid == 0) {
        float t = 0.0f;
#pragma unroll
        for (int w = 0; w < TPB / 64; ++w) t += wsum[w];
        atomicAdd(out, t);
    }
}

extern "C" void kernel_launch(void* const* d_in, const int* in_sizes, int n_in,
                              void* d_out, int out_size, void* d_ws, size_t ws_size,
                              hipStream_t stream) {
    const float* p = (const float*)d_in[0];
    const float* a = (const float*)d_in[1];
    float* out = (float*)d_out;

    const long long n_cells = (long long)in_sizes[0] / CH;   // 16384*7*7 = 802816
    const int grid = (int)((n_cells + TPB - 1) / TPB);       // 6272, exact

    // d_out is re-poisoned (0xAA) before every timed replay -> must zero it here.
    hipMemsetAsync(d_out, 0, sizeof(float), stream);
    yolo_loss_kernel<<<grid, TPB, 0, stream>>>(p, a, out, n_cells);
}

// Round 2
// 232.597 us; speedup vs baseline: 1.0563x; 1.0563x over previous
//
#include <hip/hip_runtime.h>

// YOLO-v1-style loss, exact port of the JAX reference.
// S=7, B=2, C=20, channels per cell = 30:
//   ch 0..19  : class scores
//   ch 20..24 : box0 x,y,w,h,conf
//   ch 25..29 : box1 x,y,w,h,conf
// cls part of the loss uses channels [5*B: i.e. 10..29] (reference quirk, kept).
//
// R2: stage tiles via __builtin_amdgcn_global_load_lds (16B, fully unrolled,
// no VGPR round-trip) — all 16 chunk-loads per thread in flight at once.

#define CH    30
#define EPSL  1e-6f
#define TPB   128   // threads (=cells) per block; LDS = 2*128*30*4 B = 30720 B -> 5 blocks/CU
#define NVEC  (TPB * CH / 4)   // 960 float4 per tensor tile

typedef __attribute__((address_space(3))) void       lds_void;
typedef const __attribute__((address_space(1))) void glb_void;

__device__ __forceinline__ float sgnf(float x) {
    return (x > 0.0f) ? 1.0f : ((x < 0.0f) ? -1.0f : 0.0f);
}

__global__ __launch_bounds__(TPB) void yolo_loss_kernel(const float* __restrict__ p,
                                                        const float* __restrict__ a,
                                                        float* __restrict__ out,
                                                        long long n_cells) {
    __shared__ float shp[TPB * CH];
    __shared__ float sha[TPB * CH];
    __shared__ float wsum[TPB / 64];

    const int tid = threadIdx.x;
    const long long block_cell0 = (long long)blockIdx.x * TPB;
    const long long block_base  = block_cell0 * CH;          // float offset; tile start 16B-aligned
    const long long total       = n_cells * CH;

    // ---- Stage both tiles into LDS via async DMA (global_load_lds, 16B) ----
    // lane-i destination = wave-uniform base + lane*16 (the required DMA pattern:
    // LDS byte offset idx*16 with idx = tid + TPB*k).
    const float4* gp4 = (const float4*)(p + block_base);
    const float4* ga4 = (const float4*)(a + block_base);

    int lim = NVEC;
    {   // defensive for a non-exact final tile (not hit with N=16384: 6272*128 exact)
        const long long rem4 = (total - block_base) >> 2;
        if (rem4 < NVEC) lim = (int)rem4;
    }

#pragma unroll
    for (int k = 0; k < 8; ++k) {
        const int idx = tid + TPB * k;   // k<7 always <960; k==7 wave-uniform split
        if (idx < lim) {
            __builtin_amdgcn_global_load_lds((glb_void*)(ga4 + idx),
                                             (lds_void*)&sha[idx * 4], 16, 0, 0);
        }
    }
#pragma unroll
    for (int k = 0; k < 8; ++k) {
        const int idx = tid + TPB * k;
        if (idx < lim) {
            __builtin_amdgcn_global_load_lds((glb_void*)(gp4 + idx),
                                             (lds_void*)&shp[idx * 4], 16, 0, 0);
        }
    }
    __syncthreads();   // emits s_waitcnt vmcnt(0) lgkmcnt(0) + s_barrier -> DMA drained

    float lsum = 0.0f;
    const long long cell = block_cell0 + tid;
    if (cell < n_cells) {
        const float* cp = &shp[tid * CH];
        const float* ca = &sha[tid * CH];

        float pxv[2], pyv[2], pwv[2], phv[2], pcv[2];
        float axv[2], ayv[2], awv[2], ahv[2];
#pragma unroll
        for (int b = 0; b < 2; ++b) {
            pxv[b] = cp[20 + 5 * b]; pyv[b] = cp[21 + 5 * b];
            pwv[b] = cp[22 + 5 * b]; phv[b] = cp[23 + 5 * b];
            pcv[b] = cp[24 + 5 * b];
            axv[b] = ca[20 + 5 * b]; ayv[b] = ca[21 + 5 * b];
            awv[b] = ca[22 + 5 * b]; ahv[b] = ca[23 + 5 * b];
        }
        const bool obj = ca[24] > 0.0f;   // a's box-0 conf

        // ---- pairwise IoU, max over target boxes ----
        float miou[2];
#pragma unroll
        for (int pb = 0; pb < 2; ++pb) {
            const float p_tlx = pxv[pb] - 0.5f * pwv[pb];
            const float p_tly = pyv[pb] - 0.5f * phv[pb];
            const float p_brx = pxv[pb] + 0.5f * pwv[pb];
            const float p_bry = pyv[pb] + 0.5f * phv[pb];
            const float p_area = pwv[pb] * phv[pb];
            float best = -3.4e38f;
#pragma unroll
            for (int ab = 0; ab < 2; ++ab) {
                const float a_tlx = axv[ab] - 0.5f * awv[ab];
                const float a_tly = ayv[ab] - 0.5f * ahv[ab];
                const float a_brx = axv[ab] + 0.5f * awv[ab];
                const float a_bry = ayv[ab] + 0.5f * ahv[ab];
                float sx = fminf(p_brx, a_brx) - fmaxf(p_tlx, a_tlx);
                float sy = fminf(p_bry, a_bry) - fmaxf(p_tly, a_tly);
                sx = fmaxf(sx, 0.0f);
                sy = fmaxf(sy, 0.0f);
                const float inter = sx * sy;
                const float uni = p_area + awv[ab] * ahv[ab] - inter;
                const float iou = (uni == 0.0f) ? 0.0f : (inter / uni);  // where(zero,0)/where(zero,eps)
                best = fmaxf(best, iou);
            }
            miou[pb] = best;
        }
        // argmax over pred boxes, first-max tie-break (jnp.argmax semantics)
        const int resp = (miou[1] > miou[0]) ? 1 : 0;

        // ---- coordinate / confidence losses ----
#pragma unroll
        for (int b = 0; b < 2; ++b) {
            const bool oij = obj && (b == resp);
            if (oij) {
                const float dx = axv[b] - pxv[b];
                const float dy = ayv[b] - pyv[b];
                const float dw = sgnf(awv[b]) * sqrtf(awv[b] + EPSL) - sgnf(pwv[b]) * sqrtf(pwv[b] + EPSL);
                const float dh = sgnf(ahv[b]) * sqrtf(ahv[b] + EPSL) - sgnf(phv[b]) * sqrtf(phv[b] + EPSL);
                const float dc = 1.0f - pcv[b];  // (obj_ij^2 - obj_ij*pc)^2 with obj_ij==1
                lsum += 5.0f * (dx * dx + dy * dy + dw * dw + dh * dh) + dc * dc;
            } else {
                // noobj term: (noobj_ij*obj_ij - noobj_ij*pc)^2 = pc^2 when obj_ij==0
                lsum += 0.5f * pcv[b] * pcv[b];
            }
        }

        // ---- "class" loss over channels 10..29, gated by obj_i ----
        if (obj) {
#pragma unroll
            for (int k = 10; k < 30; ++k) {
                const float d = cp[k] - ca[k];
                lsum += d * d;
            }
        }
    }

    // ---- reduction: wave shfl -> LDS -> one atomic per block ----
    float v = lsum;
#pragma unroll
    for (int off = 32; off > 0; off >>= 1)
        v += __shfl_down(v, off, 64);
    if ((tid & 63) == 0) wsum[tid >> 6] = v;
    __syncthreads();
    if (tid == 0) {
        float t = 0.0f;
#pragma unroll
        for (int w = 0; w < TPB / 64; ++w) t += wsum[w];
        atomicAdd(out, t);
    }
}

extern "C" void kernel_launch(void* const* d_in, const int* in_sizes, int n_in,
                              void* d_out, int out_size, void* d_ws, size_t ws_size,
                              hipStream_t stream) {
    const float* p = (const float*)d_in[0];
    const float* a = (const float*)d_in[1];
    float* out = (float*)d_out;

    const long long n_cells = (long long)in_sizes[0] / CH;   // 16384*7*7 = 802816
    const int grid = (int)((n_cells + TPB - 1) / TPB);       // 6272, exact

    // d_out is re-poisoned (0xAA) before every timed replay -> must zero it here.
    hipMemsetAsync(d_out, 0, sizeof(float), stream);
    yolo_loss_kernel<<<grid, TPB, 0, stream>>>(p, a, out, n_cells);
}

// Round 3
// 203.810 us; speedup vs baseline: 1.2055x; 1.1412x over previous
//
#include <hip/hip_runtime.h>

// YOLO-v1-style loss, exact port of the JAX reference.
// S=7, B=2, C=20, channels per cell = 30:
//   ch 0..19  : class scores
//   ch 20..24 : box0 x,y,w,h,conf
//   ch 25..29 : box1 x,y,w,h,conf
// cls part of the loss uses channels [5*B: i.e. 10..29] (reference quirk, kept).
//
// R3: NO LDS staging. Channels 0..9 are dead (loss only touches 10..29), so
// each thread direct-loads its cell's channels 10..29 as 10 independent
// float2 loads per tensor (base+40B is 8-aligned). No barrier, no LDS cap ->
// ~24 waves/CU hide the strided-load latency.

#define CH    30
#define EPSL  1e-6f
#define TPB   256

__device__ __forceinline__ float sgnf(float x) {
    return (x > 0.0f) ? 1.0f : ((x < 0.0f) ? -1.0f : 0.0f);
}

__global__ __launch_bounds__(TPB) void yolo_loss_kernel(const float* __restrict__ p,
                                                        const float* __restrict__ a,
                                                        float* __restrict__ out,
                                                        long long n_cells) {
    __shared__ float wsum[TPB / 64];

    const int tid = threadIdx.x;
    const long long cell = (long long)blockIdx.x * TPB + tid;

    float lsum = 0.0f;
    if (cell < n_cells) {
        // pd[j] / ad[j] = channel (10+j) of this cell, j in [0,20)
        const float2* cp2 = (const float2*)(p + cell * CH + 10);
        const float2* ca2 = (const float2*)(a + cell * CH + 10);
        float pd[20], ad[20];
#pragma unroll
        for (int i = 0; i < 10; ++i) {
            const float2 v = cp2[i];
            pd[2 * i] = v.x; pd[2 * i + 1] = v.y;
        }
#pragma unroll
        for (int i = 0; i < 10; ++i) {
            const float2 v = ca2[i];
            ad[2 * i] = v.x; ad[2 * i + 1] = v.y;
        }

        // box attrs: channel 20+5b+i -> index 10+5b+i
        float pxv[2], pyv[2], pwv[2], phv[2], pcv[2];
        float axv[2], ayv[2], awv[2], ahv[2];
#pragma unroll
        for (int b = 0; b < 2; ++b) {
            pxv[b] = pd[10 + 5 * b]; pyv[b] = pd[11 + 5 * b];
            pwv[b] = pd[12 + 5 * b]; phv[b] = pd[13 + 5 * b];
            pcv[b] = pd[14 + 5 * b];
            axv[b] = ad[10 + 5 * b]; ayv[b] = ad[11 + 5 * b];
            awv[b] = ad[12 + 5 * b]; ahv[b] = ad[13 + 5 * b];
        }
        const bool obj = ad[14] > 0.0f;   // a's box-0 conf (channel 24)

        // ---- pairwise IoU, max over target boxes ----
        float miou[2];
#pragma unroll
        for (int pb = 0; pb < 2; ++pb) {
            const float p_tlx = pxv[pb] - 0.5f * pwv[pb];
            const float p_tly = pyv[pb] - 0.5f * phv[pb];
            const float p_brx = pxv[pb] + 0.5f * pwv[pb];
            const float p_bry = pyv[pb] + 0.5f * phv[pb];
            const float p_area = pwv[pb] * phv[pb];
            float best = -3.4e38f;
#pragma unroll
            for (int ab = 0; ab < 2; ++ab) {
                const float a_tlx = axv[ab] - 0.5f * awv[ab];
                const float a_tly = ayv[ab] - 0.5f * ahv[ab];
                const float a_brx = axv[ab] + 0.5f * awv[ab];
                const float a_bry = ayv[ab] + 0.5f * ahv[ab];
                float sx = fminf(p_brx, a_brx) - fmaxf(p_tlx, a_tlx);
                float sy = fminf(p_bry, a_bry) - fmaxf(p_tly, a_tly);
                sx = fmaxf(sx, 0.0f);
                sy = fmaxf(sy, 0.0f);
                const float inter = sx * sy;
                const float uni = p_area + awv[ab] * ahv[ab] - inter;
                const float iou = (uni == 0.0f) ? 0.0f : (inter / uni);  // where(zero,0)/where(zero,eps)
                best = fmaxf(best, iou);
            }
            miou[pb] = best;
        }
        // argmax over pred boxes, first-max tie-break (jnp.argmax semantics)
        const int resp = (miou[1] > miou[0]) ? 1 : 0;

        // ---- coordinate / confidence losses ----
#pragma unroll
        for (int b = 0; b < 2; ++b) {
            const bool oij = obj && (b == resp);
            if (oij) {
                const float dx = axv[b] - pxv[b];
                const float dy = ayv[b] - pyv[b];
                const float dw = sgnf(awv[b]) * sqrtf(awv[b] + EPSL) - sgnf(pwv[b]) * sqrtf(pwv[b] + EPSL);
                const float dh = sgnf(ahv[b]) * sqrtf(ahv[b] + EPSL) - sgnf(phv[b]) * sqrtf(phv[b] + EPSL);
                const float dc = 1.0f - pcv[b];  // (obj_ij^2 - obj_ij*pc)^2 with obj_ij==1
                lsum += 5.0f * (dx * dx + dy * dy + dw * dw + dh * dh) + dc * dc;
            } else {
                // noobj term: (noobj_ij*obj_ij - noobj_ij*pc)^2 = pc^2 when obj_ij==0
                lsum += 0.5f * pcv[b] * pcv[b];
            }
        }

        // ---- "class" loss over channels 10..29 (indices 0..19), gated by obj_i ----
        if (obj) {
#pragma unroll
            for (int k = 0; k < 20; ++k) {
                const float d = pd[k] - ad[k];
                lsum += d * d;
            }
        }
    }

    // ---- reduction: wave shfl -> LDS -> one atomic per block ----
    float v = lsum;
#pragma unroll
    for (int off = 32; off > 0; off >>= 1)
        v += __shfl_down(v, off, 64);
    if ((tid & 63) == 0) wsum[tid >> 6] = v;
    __syncthreads();
    if (tid == 0) {
        float t = 0.0f;
#pragma unroll
        for (int w = 0; w < TPB / 64; ++w) t += wsum[w];
        atomicAdd(out, t);
    }
}

extern "C" void kernel_launch(void* const* d_in, const int* in_sizes, int n_in,
                              void* d_out, int out_size, void* d_ws, size_t ws_size,
                              hipStream_t stream) {
    const float* p = (const float*)d_in[0];
    const float* a = (const float*)d_in[1];
    float* out = (float*)d_out;

    const long long n_cells = (long long)in_sizes[0] / CH;   // 16384*7*7 = 802816
    const int grid = (int)((n_cells + TPB - 1) / TPB);       // 3136, exact

    // d_out is re-poisoned (0xAA) before every timed replay -> must zero it here.
    hipMemsetAsync(d_out, 0, sizeof(float), stream);
    yolo_loss_kernel<<<grid, TPB, 0, stream>>>(p, a, out, n_cells);
}